// Round 6
// baseline (233.217 us; speedup 1.0000x reference)
//
#include <hip/hip_runtime.h>
#include <hip/hip_bf16.h>
#include <math.h>

#define Nn    512
#define CS    384
#define CZ    128
#define CH    16
#define Hh    12
#define PQ    4
#define PV    8
#define NCOL  1152   // 192*3 + 144*2 + 288
#define FIN   2112

#define W_C   0.23570226039551584f   // sqrt(2/(9*4))
#define W_L   0.5773502691896258f    // sqrt(1/3)

typedef unsigned short ushort_t;
typedef __attribute__((ext_vector_type(8))) short bf16x8;
typedef __attribute__((ext_vector_type(4))) float f32x4;

// ---------------- workspace layout (float offsets) ----------------
#define OFF_P      0u           // N x 1152 raw projections (f32)
#define OFF_MQ     589824u      // unused by fused kernel (kept)
#define OFF_MK     595968u
#define OFF_VT     602112u      // v16T  [192][512] bf16
#define OFF_VPT    651264u      // vpgT  [288][512] bf16
#define OFF_FEAT   749568u      // N x 2112 f32
#define OFF_LOG    1830912u     // K5 partials (8 x N x 384 f32)
#define OFF_EKB    21755904u
#define OFF_EQB    21854208u
#define OFF_WBF    21952512u

__device__ inline ushort_t f2bf(float f) {
  __hip_bfloat16 h = __float2bfloat16(f);
  return *reinterpret_cast<ushort_t*>(&h);
}
__device__ inline float bf2f(ushort_t u) {
  unsigned int x = ((unsigned int)u) << 16;
  return __uint_as_float(x);
}

// ================= K1: projections  P = s_i @ [Wq|Wk|Wv|Wqp|Wkp|Wvp] =========
__global__ __launch_bounds__(384) void k_proj(
    const float* __restrict__ s, const float* __restrict__ Wq,
    const float* __restrict__ Wk, const float* __restrict__ Wv,
    const float* __restrict__ Wqp, const float* __restrict__ Wkp,
    const float* __restrict__ Wvp, float* __restrict__ P) {
  int col = blockIdx.x * 384 + threadIdx.x;       // 0..1151
  int i0  = blockIdx.y * 8;
  const float* base; int stride, off;
  if      (col < 192) { base = Wq;  stride = 192; off = col;       }
  else if (col < 384) { base = Wk;  stride = 192; off = col - 192; }
  else if (col < 576) { base = Wv;  stride = 192; off = col - 384; }
  else if (col < 720) { base = Wqp; stride = 144; off = col - 576; }
  else if (col < 864) { base = Wkp; stride = 144; off = col - 720; }
  else                { base = Wvp; stride = 288; off = col - 864; }
  float acc[8];
#pragma unroll
  for (int ii = 0; ii < 8; ++ii) acc[ii] = 0.f;
  const float* bp = base + off;
#pragma unroll 4
  for (int k = 0; k < CS; ++k) {
    float w = bp[k * stride];
#pragma unroll
    for (int ii = 0; ii < 8; ++ii) acc[ii] += w * s[(i0 + ii) * CS + k];
  }
#pragma unroll
  for (int ii = 0; ii < 8; ++ii) P[(size_t)(i0 + ii) * NCOL + col] = acc[ii];
}

// ===== K1b: rigid transforms -> eqb/ekb bf16, mq/mk, v16T, vpgT =============
__global__ __launch_bounds__(64) void k_prep(
    const float* __restrict__ P, const float* __restrict__ rot,
    const float* __restrict__ trans, const float* __restrict__ gamma,
    ushort_t* __restrict__ eqb, ushort_t* __restrict__ ekb,
    float* __restrict__ mq, float* __restrict__ mk,
    ushort_t* __restrict__ vT, ushort_t* __restrict__ vpT) {
  int gid = blockIdx.x * 64 + threadIdx.x;        // < 6144
  int i = gid / Hh, h = gid % Hh;
  const float* Pi = P + (size_t)i * NCOL;
  float R[9], T[3];
#pragma unroll
  for (int m = 0; m < 9; ++m) R[m] = rot[i * 9 + m];
#pragma unroll
  for (int m = 0; m < 3; ++m) T[m] = trans[i * 3 + m];
  float cg = W_C * gamma[h];

  ushort_t* eq = eqb + (size_t)gid * 32;
  ushort_t* ek = ekb + (size_t)gid * 32;
#pragma unroll
  for (int d = 0; d < CH; ++d) eq[d] = f2bf(Pi[h * CH + d] * 0.25f);   // q/sqrt(16)
#pragma unroll
  for (int d = 0; d < CH; ++d) ek[d] = f2bf(Pi[192 + h * CH + d]);     // k
  float sq = 0.f, sk = 0.f;
#pragma unroll
  for (int p = 0; p < PQ; ++p) {
    float x = Pi[576 + h * 12 + p * 3 + 0];
    float y = Pi[576 + h * 12 + p * 3 + 1];
    float zc = Pi[576 + h * 12 + p * 3 + 2];
    float gx = R[0] * x + R[1] * y + R[2] * zc + T[0];
    float gy = R[3] * x + R[4] * y + R[5] * zc + T[1];
    float gz = R[6] * x + R[7] * y + R[8] * zc + T[2];
    eq[16 + p * 3 + 0] = f2bf(cg * gx);
    eq[16 + p * 3 + 1] = f2bf(cg * gy);
    eq[16 + p * 3 + 2] = f2bf(cg * gz);
    sq += gx * gx + gy * gy + gz * gz;
  }
#pragma unroll
  for (int p = 0; p < PQ; ++p) {
    float x = Pi[720 + h * 12 + p * 3 + 0];
    float y = Pi[720 + h * 12 + p * 3 + 1];
    float zc = Pi[720 + h * 12 + p * 3 + 2];
    float gx = R[0] * x + R[1] * y + R[2] * zc + T[0];
    float gy = R[3] * x + R[4] * y + R[5] * zc + T[1];
    float gz = R[6] * x + R[7] * y + R[8] * zc + T[2];
    ek[16 + p * 3 + 0] = f2bf(gx);
    ek[16 + p * 3 + 1] = f2bf(gy);
    ek[16 + p * 3 + 2] = f2bf(gz);
    sk += gx * gx + gy * gy + gz * gz;
  }
#pragma unroll
  for (int d = 28; d < 32; ++d) { eq[d] = 0; ek[d] = 0; }
  mq[gid] = -0.5f * cg * sq;
  mk[gid] = -0.5f * cg * sk;

#pragma unroll
  for (int d = 0; d < CH; ++d)
    vT[(size_t)(h * CH + d) * Nn + i] = f2bf(Pi[384 + h * CH + d]);
#pragma unroll
  for (int p = 0; p < PV; ++p) {
    float x = Pi[864 + h * 24 + p * 3 + 0];
    float y = Pi[864 + h * 24 + p * 3 + 1];
    float zc = Pi[864 + h * 24 + p * 3 + 2];
    vpT[(size_t)(h * 24 + p * 3 + 0) * Nn + i] = f2bf(R[0] * x + R[1] * y + R[2] * zc + T[0]);
    vpT[(size_t)(h * 24 + p * 3 + 1) * Nn + i] = f2bf(R[3] * x + R[4] * y + R[5] * zc + T[1]);
    vpT[(size_t)(h * 24 + p * 3 + 2) * Nn + i] = f2bf(R[6] * x + R[7] * y + R[8] * zc + T[2]);
  }
}

// ===== K1c: Wb B-fragments (dense): wbf[kk][lane][e] for 16x16x32 MFMA ======
__global__ __launch_bounds__(256) void k_wbfrag(
    const float* __restrict__ Wb, ushort_t* __restrict__ wbf) {
  int t = threadIdx.x;            // 256 = 4 ksteps * 64 lanes
  int kk = t >> 6, l = t & 63;
  int h = l & 15, lk = l >> 4;
#pragma unroll
  for (int e = 0; e < 8; ++e) {
    int c = kk * 32 + lk * 8 + e;
    wbf[t * 8 + e] = (h < Hh) ? f2bf(Wb[c * Hh + h]) : (ushort_t)0;
  }
}

// ======== K2: per-wave flash fused kernel, block per i, 8 waves ==============
// Wave w owns j in [w*64, w*64+64), 2 chunks of 32. No barriers in main loop.
// LDS: [0,64K) per-wave z-stage (8KB each; doubles as accbuf[16][608] at merge)
//      [64K,74K) per-wave pbuf (16 x 40 halves); [74K+) m/l/M/Linv
__global__ __launch_bounds__(512) void k_fused2(
    const float* __restrict__ z, const ushort_t* __restrict__ eqb,
    const ushort_t* __restrict__ ekb, const ushort_t* __restrict__ wbf,
    const float* __restrict__ mk,
    const ushort_t* __restrict__ vT, const ushort_t* __restrict__ vpT,
    const float* __restrict__ rot, const float* __restrict__ trans,
    float* __restrict__ feat) {
  __shared__ float smemf[19232];                   // 76928 B

  int i = blockIdx.x, tid = threadIdx.x;
  int l = tid & 63, w = tid >> 6;                  // 8 waves
  int cl = l & 15, lk = l >> 4;
  float* Fi = feat + (size_t)i * FIN;
  const float* zbase = z + (size_t)i * Nn * CZ;

  ushort_t* ztw = (ushort_t*)smemf + w * 4096;     // 8KB per wave: [32][128] swz
  float*    accb = smemf;                          // [16][608] (merge phase)
  ushort_t* pbw = (ushort_t*)(smemf + 16384) + w * 640;  // [16][40] halves
  float*    mb  = smemf + 18944;                   // [8][16]
  float*    lb  = smemf + 19072;                   // [8][16]
  float*    Mv  = smemf + 19200;                   // [16]
  float*    Lv  = smemf + 19216;                   // [16] (1/L)

  bf16x8 zer;
#pragma unroll
  for (int e = 0; e < 8; ++e) zer[e] = 0;

  // hoisted B-frags
  bf16x8 wbreg[4];
#pragma unroll
  for (int kk = 0; kk < 4; ++kk)
    wbreg[kk] = *(const bf16x8*)&wbf[(kk * 64 + l) * 8];
  bf16x8 eqsel = zer;
  if (cl < Hh) eqsel = *(const bf16x8*)&eqb[((size_t)i * Hh + cl) * 32 + lk * 8];

  float m_run = -1e30f, l_run = 0.f;               // per head = cl
  f32x4 acc[38];
#pragma unroll
  for (int t = 0; t < 38; ++t) acc[t] = (f32x4){0.f, 0.f, 0.f, 0.f};

  for (int c = 0; c < 2; ++c) {
    int j0c = w * 64 + c * 32;                     // this wave's j-chunk

    // ---- stage 32 rows of z: f32 -> bf16 -> private LDS (swizzled) ----
    const float4* zg4 = (const float4*)(zbase + (size_t)j0c * CZ);
#pragma unroll
    for (int m = 0; m < 8; ++m) {
      int idx = m * 128 + l * 2;
      float4 A4 = zg4[idx], B4 = zg4[idx + 1];
      int row = m * 4 + lk, c8 = cl;
      bf16x8 p;
      p[0] = (short)f2bf(A4.x); p[1] = (short)f2bf(A4.y);
      p[2] = (short)f2bf(A4.z); p[3] = (short)f2bf(A4.w);
      p[4] = (short)f2bf(B4.x); p[5] = (short)f2bf(B4.y);
      p[6] = (short)f2bf(B4.z); p[7] = (short)f2bf(B4.w);
      *(bf16x8*)&ztw[row * 128 + ((c8 ^ (row & 7)) << 3)] = p;
    }

    // ---- logits: 2 groups of 16 j-rows ----
    float v[2][4];
#pragma unroll
    for (int g = 0; g < 2; ++g) {
      int jrl = g * 16 + cl;                       // A row (tile-local j)
      int jg = j0c + jrl;                          // global j
      f32x4 dl = {0.f, 0.f, 0.f, 0.f};
#pragma unroll
      for (int kk = 0; kk < 4; ++kk) {
        int c8 = kk * 4 + lk;
        bf16x8 a = *(const bf16x8*)&ztw[jrl * 128 + ((c8 ^ (jrl & 7)) << 3)];
        dl = __builtin_amdgcn_mfma_f32_16x16x32_bf16(a, wbreg[kk], dl, 0, 0, 0);
      }
#pragma unroll
      for (int hp = 0; hp < Hh; ++hp) {
        bf16x8 a = *(const bf16x8*)&ekb[((size_t)jg * Hh + hp) * 32 + lk * 8];
        bf16x8 b = (cl == hp) ? eqsel : zer;
        dl = __builtin_amdgcn_mfma_f32_16x16x32_bf16(a, b, dl, 0, 0, 0);
      }
      int jb = j0c + g * 16 + lk * 4;
      if (cl < Hh) {
#pragma unroll
        for (int r = 0; r < 4; ++r) v[g][r] = W_L * (dl[r] + mk[(jb + r) * Hh + cl]);
      } else {
#pragma unroll
        for (int r = 0; r < 4; ++r) v[g][r] = -1e30f;
      }
    }

    // ---- per-wave online softmax (head = cl) ----
    float mx = v[0][0];
#pragma unroll
    for (int g = 0; g < 2; ++g)
#pragma unroll
      for (int r = 0; r < 4; ++r) mx = fmaxf(mx, v[g][r]);
    mx = fmaxf(mx, __shfl_xor(mx, 16));
    mx = fmaxf(mx, __shfl_xor(mx, 32));
    float m_new = fmaxf(m_run, mx);
    float sc = __expf(m_run - m_new);
    m_run = m_new;

    float ps = 0.f;
#pragma unroll
    for (int g = 0; g < 2; ++g) {
      unsigned int d0, d1;
      ushort_t pb0 = f2bf(__expf(v[g][0] - m_run));
      ushort_t pb1 = f2bf(__expf(v[g][1] - m_run));
      ushort_t pb2 = f2bf(__expf(v[g][2] - m_run));
      ushort_t pb3 = f2bf(__expf(v[g][3] - m_run));
      ps += bf2f(pb0) + bf2f(pb1) + bf2f(pb2) + bf2f(pb3);
      d0 = (unsigned int)pb0 | ((unsigned int)pb1 << 16);
      d1 = (unsigned int)pb2 | ((unsigned int)pb3 << 16);
      *(uint2*)&pbw[cl * 40 + g * 16 + lk * 4] = make_uint2(d0, d1);
    }
    ps += __shfl_xor(ps, 16);
    ps += __shfl_xor(ps, 32);
    l_run = l_run * sc + ps;

    // rescale acc by per-head factor (head of acc row r is lk*4+r)
    float sc_r[4];
#pragma unroll
    for (int r = 0; r < 4; ++r) sc_r[r] = __shfl(sc, lk * 4 + r);
#pragma unroll
    for (int t = 0; t < 38; ++t) {
#pragma unroll
      for (int r = 0; r < 4; ++r) acc[t][r] *= sc_r[r];
    }

    // ---- attend: A = P[head][j0c..+31], one K=32 step, all 38 col-tiles ----
    bf16x8 af = *(const bf16x8*)&pbw[cl * 40 + lk * 8];
#pragma unroll
    for (int t = 0; t < 38; ++t) {
      bf16x8 bf;
      if (t < 8) {                                 // o_pair: transposed ztw read
        int cc = t * 16 + cl;
#pragma unroll
        for (int e = 0; e < 8; ++e) {
          int rr = lk * 8 + e;
          bf[e] = (short)ztw[rr * 128 + ((((cc >> 3) ^ (rr & 7)) << 3) | (cc & 7))];
        }
      } else if (t < 20) {                         // o_sc
        bf = *(const bf16x8*)(vT + (size_t)((t - 8) * 16 + cl) * Nn + j0c + lk * 8);
      } else {                                     // o_pt
        bf = *(const bf16x8*)(vpT + (size_t)((t - 20) * 16 + cl) * Nn + j0c + lk * 8);
      }
      acc[t] = __builtin_amdgcn_mfma_f32_16x16x32_bf16(af, bf, acc[t], 0, 0, 0);
    }
  }

  // ================= merge across waves =================
  if (l < 16) { mb[w * 16 + cl] = m_run; lb[w * 16 + cl] = l_run; }
  __syncthreads();                                 // #1

  for (int idx = tid; idx < 16 * 608; idx += 512) accb[idx] = 0.f;
  if (tid < 16) {
    float M = mb[tid];
#pragma unroll
    for (int ww = 1; ww < 8; ++ww) M = fmaxf(M, mb[ww * 16 + tid]);
    float L = 0.f;
#pragma unroll
    for (int ww = 0; ww < 8; ++ww) L += lb[ww * 16 + tid] * __expf(mb[ww * 16 + tid] - M);
    Mv[tid] = M;
    Lv[tid] = 1.f / L;
  }
  __syncthreads();                                 // #2

  float sf[4];
#pragma unroll
  for (int r = 0; r < 4; ++r) {
    int h = lk * 4 + r;
    float mw = __shfl(m_run, h);
    sf[r] = __expf(mw - Mv[h]);
  }
#pragma unroll
  for (int t = 0; t < 38; ++t) {
    int cc = t * 16 + cl;
#pragma unroll
    for (int r = 0; r < 4; ++r) {
      int h = lk * 4 + r;
      bool use;
      if (t < 8)        use = (h < Hh);
      else if (t < 20)  use = (h == t - 8);
      else              use = (h == (cc - 320) / 24);
      if (use) atomicAdd(&accb[h * 608 + cc], acc[t][r] * sf[r]);
    }
  }
  __syncthreads();                                 // #3

  // ---- write out (normalize by 1/L) ----
  for (int idx = tid; idx < 1728; idx += 512) {
    if (idx < 1536) {
      int h = idx >> 7;
      Fi[idx] = accb[h * 608 + (idx & 127)] * Lv[h];
    } else {
      int c2 = idx - 1536;
      int h = c2 >> 4;
      Fi[idx] = accb[h * 608 + 128 + c2] * Lv[h];
    }
  }
  if (tid < 96) {
    int h = tid >> 3, p = tid & 7;
    int cp = h * 24 + p * 3;
    float li = Lv[h];
    float g0 = accb[h * 608 + 320 + cp + 0] * li - trans[i * 3 + 0];
    float g1 = accb[h * 608 + 320 + cp + 1] * li - trans[i * 3 + 1];
    float g2 = accb[h * 608 + 320 + cp + 2] * li - trans[i * 3 + 2];
    const float* R = rot + i * 9;
    float ss = 0.f;
#pragma unroll
    for (int nn2 = 0; nn2 < 3; ++nn2) {
      float o = R[nn2] * g0 + R[3 + nn2] * g1 + R[6 + nn2] * g2;   // R^T (g - t)
      Fi[1728 + cp + nn2] = o;
      ss += o * o;
    }
    Fi[2016 + h * 8 + p] = sqrtf(ss + 1e-12f);
  }
}

// ============ K5a: out partials  part[fs][i][o] = feat[f-slice] @ Wf ========
__global__ __launch_bounds__(384) void k_out_partial(
    const float* __restrict__ feat, const float* __restrict__ Wf,
    float* __restrict__ part) {
  int fs = blockIdx.x;                     // 0..7 (f-slice of 264)
  int i0 = blockIdx.y * 8;
  int o = threadIdx.x;                     // 0..383
  float acc[8];
#pragma unroll
  for (int ii = 0; ii < 8; ++ii) acc[ii] = 0.f;
  int f0 = fs * 264;
#pragma unroll 4
  for (int f = f0; f < f0 + 264; ++f) {
    float w = Wf[(size_t)f * CS + o];
#pragma unroll
    for (int ii = 0; ii < 8; ++ii) acc[ii] += w * feat[(size_t)(i0 + ii) * FIN + f];
  }
#pragma unroll
  for (int ii = 0; ii < 8; ++ii)
    part[((size_t)fs * Nn + i0 + ii) * CS + o] = acc[ii];
}

// ============ K5b: reduce partials + bias -> out ============================
__global__ __launch_bounds__(256) void k_out_reduce(
    const float* __restrict__ part, const float* __restrict__ bf,
    float* __restrict__ out) {
  int idx = blockIdx.x * 256 + threadIdx.x;        // < 512*384
  float s = bf[idx % CS];
#pragma unroll
  for (int fs = 0; fs < 8; ++fs) s += part[(size_t)fs * (Nn * CS) + idx];
  out[idx] = s;
}

// ============================ launcher ======================================
extern "C" void kernel_launch(void* const* d_in, const int* in_sizes, int n_in,
                              void* d_out, int out_size, void* d_ws, size_t ws_size,
                              hipStream_t stream) {
  const float* s_i   = (const float*)d_in[0];
  const float* z_ij  = (const float*)d_in[1];
  const float* rot   = (const float*)d_in[2];
  const float* trans = (const float*)d_in[3];
  const float* Wq    = (const float*)d_in[4];
  const float* Wk    = (const float*)d_in[5];
  const float* Wv    = (const float*)d_in[6];
  const float* Wqp   = (const float*)d_in[7];
  const float* Wkp   = (const float*)d_in[8];
  const float* Wvp   = (const float*)d_in[9];
  const float* Wb    = (const float*)d_in[10];
  const float* gamma = (const float*)d_in[11];
  const float* Wf    = (const float*)d_in[12];
  const float* bf    = (const float*)d_in[13];
  float* out = (float*)d_out;

  float* w = (float*)d_ws;
  float*    P    = w + OFF_P;
  float*    mq   = w + OFF_MQ;
  float*    mk   = w + OFF_MK;
  ushort_t* vT   = (ushort_t*)(w + OFF_VT);
  ushort_t* vpT  = (ushort_t*)(w + OFF_VPT);
  float*    feat = w + OFF_FEAT;
  float*    lg   = w + OFF_LOG;     // K5 partials
  ushort_t* ekb  = (ushort_t*)(w + OFF_EKB);
  ushort_t* eqb  = (ushort_t*)(w + OFF_EQB);
  ushort_t* wbf  = (ushort_t*)(w + OFF_WBF);

  k_proj<<<dim3(3, 64), 384, 0, stream>>>(s_i, Wq, Wk, Wv, Wqp, Wkp, Wvp, P);
  k_prep<<<96, 64, 0, stream>>>(P, rot, trans, gamma, eqb, ekb, mq, mk, vT, vpT);
  k_wbfrag<<<1, 256, 0, stream>>>(Wb, wbf);
  k_fused2<<<512, 512, 0, stream>>>(z_ij, eqb, ekb, wbf, mk, vT, vpT, rot, trans, feat);
  k_out_partial<<<dim3(8, 64), 384, 0, stream>>>(feat, Wf, lg);
  k_out_reduce<<<768, 256, 0, stream>>>(lg, bf, out);
}

// Round 7
// 167.381 us; speedup vs baseline: 1.3933x; 1.3933x over previous
//
#include <hip/hip_runtime.h>
#include <hip/hip_bf16.h>
#include <math.h>

#define Nn    512
#define CS    384
#define CZ    128
#define CH    16
#define Hh    12
#define PQ    4
#define PV    8
#define NCOL  1152   // 192*3 + 144*2 + 288
#define FIN   2112

#define W_C   0.23570226039551584f   // sqrt(2/(9*4))
#define W_L   0.5773502691896258f    // sqrt(1/3)

typedef unsigned short ushort_t;
typedef __attribute__((ext_vector_type(8))) short bf16x8;
typedef __attribute__((ext_vector_type(4))) float f32x4;

// ---------------- workspace layout (float offsets) ----------------
#define OFF_P      0u           // N x 1152 raw projections (f32)
#define OFF_MQ     589824u      // unused by fused kernel (kept)
#define OFF_MK     595968u
#define OFF_VT     602112u      // v16T  [192][512] bf16
#define OFF_VPT    651264u      // vpgT  [288][512] bf16
#define OFF_FEAT   749568u      // N x 2112 f32
#define OFF_LOG    1830912u     // K5 partials (8 x N x 384 f32)
#define OFF_EKB    21755904u
#define OFF_EQB    21854208u
#define OFF_WBF    21952512u

__device__ inline ushort_t f2bf(float f) {
  __hip_bfloat16 h = __float2bfloat16(f);
  return *reinterpret_cast<ushort_t*>(&h);
}
__device__ inline float bf2f(ushort_t u) {
  unsigned int x = ((unsigned int)u) << 16;
  return __uint_as_float(x);
}

// ================= K1: projections  P = s_i @ [Wq|Wk|Wv|Wqp|Wkp|Wvp] =========
__global__ __launch_bounds__(384) void k_proj(
    const float* __restrict__ s, const float* __restrict__ Wq,
    const float* __restrict__ Wk, const float* __restrict__ Wv,
    const float* __restrict__ Wqp, const float* __restrict__ Wkp,
    const float* __restrict__ Wvp, float* __restrict__ P) {
  int col = blockIdx.x * 384 + threadIdx.x;       // 0..1151
  int i0  = blockIdx.y * 8;
  const float* base; int stride, off;
  if      (col < 192) { base = Wq;  stride = 192; off = col;       }
  else if (col < 384) { base = Wk;  stride = 192; off = col - 192; }
  else if (col < 576) { base = Wv;  stride = 192; off = col - 384; }
  else if (col < 720) { base = Wqp; stride = 144; off = col - 576; }
  else if (col < 864) { base = Wkp; stride = 144; off = col - 720; }
  else                { base = Wvp; stride = 288; off = col - 864; }
  float acc[8];
#pragma unroll
  for (int ii = 0; ii < 8; ++ii) acc[ii] = 0.f;
  const float* bp = base + off;
#pragma unroll 4
  for (int k = 0; k < CS; ++k) {
    float w = bp[k * stride];
#pragma unroll
    for (int ii = 0; ii < 8; ++ii) acc[ii] += w * s[(i0 + ii) * CS + k];
  }
#pragma unroll
  for (int ii = 0; ii < 8; ++ii) P[(size_t)(i0 + ii) * NCOL + col] = acc[ii];
}

// ===== K1b: rigid transforms -> eqb/ekb bf16, mq/mk, v16T, vpgT =============
__global__ __launch_bounds__(64) void k_prep(
    const float* __restrict__ P, const float* __restrict__ rot,
    const float* __restrict__ trans, const float* __restrict__ gamma,
    ushort_t* __restrict__ eqb, ushort_t* __restrict__ ekb,
    float* __restrict__ mq, float* __restrict__ mk,
    ushort_t* __restrict__ vT, ushort_t* __restrict__ vpT) {
  int gid = blockIdx.x * 64 + threadIdx.x;        // < 6144
  int i = gid / Hh, h = gid % Hh;
  const float* Pi = P + (size_t)i * NCOL;
  float R[9], T[3];
#pragma unroll
  for (int m = 0; m < 9; ++m) R[m] = rot[i * 9 + m];
#pragma unroll
  for (int m = 0; m < 3; ++m) T[m] = trans[i * 3 + m];
  float cg = W_C * gamma[h];

  ushort_t* eq = eqb + (size_t)gid * 32;
  ushort_t* ek = ekb + (size_t)gid * 32;
#pragma unroll
  for (int d = 0; d < CH; ++d) eq[d] = f2bf(Pi[h * CH + d] * 0.25f);   // q/sqrt(16)
#pragma unroll
  for (int d = 0; d < CH; ++d) ek[d] = f2bf(Pi[192 + h * CH + d]);     // k
  float sq = 0.f, sk = 0.f;
#pragma unroll
  for (int p = 0; p < PQ; ++p) {
    float x = Pi[576 + h * 12 + p * 3 + 0];
    float y = Pi[576 + h * 12 + p * 3 + 1];
    float zc = Pi[576 + h * 12 + p * 3 + 2];
    float gx = R[0] * x + R[1] * y + R[2] * zc + T[0];
    float gy = R[3] * x + R[4] * y + R[5] * zc + T[1];
    float gz = R[6] * x + R[7] * y + R[8] * zc + T[2];
    eq[16 + p * 3 + 0] = f2bf(cg * gx);
    eq[16 + p * 3 + 1] = f2bf(cg * gy);
    eq[16 + p * 3 + 2] = f2bf(cg * gz);
    sq += gx * gx + gy * gy + gz * gz;
  }
#pragma unroll
  for (int p = 0; p < PQ; ++p) {
    float x = Pi[720 + h * 12 + p * 3 + 0];
    float y = Pi[720 + h * 12 + p * 3 + 1];
    float zc = Pi[720 + h * 12 + p * 3 + 2];
    float gx = R[0] * x + R[1] * y + R[2] * zc + T[0];
    float gy = R[3] * x + R[4] * y + R[5] * zc + T[1];
    float gz = R[6] * x + R[7] * y + R[8] * zc + T[2];
    ek[16 + p * 3 + 0] = f2bf(gx);
    ek[16 + p * 3 + 1] = f2bf(gy);
    ek[16 + p * 3 + 2] = f2bf(gz);
    sk += gx * gx + gy * gy + gz * gz;
  }
#pragma unroll
  for (int d = 28; d < 32; ++d) { eq[d] = 0; ek[d] = 0; }
  mq[gid] = -0.5f * cg * sq;
  mk[gid] = -0.5f * cg * sk;

#pragma unroll
  for (int d = 0; d < CH; ++d)
    vT[(size_t)(h * CH + d) * Nn + i] = f2bf(Pi[384 + h * CH + d]);
#pragma unroll
  for (int p = 0; p < PV; ++p) {
    float x = Pi[864 + h * 24 + p * 3 + 0];
    float y = Pi[864 + h * 24 + p * 3 + 1];
    float zc = Pi[864 + h * 24 + p * 3 + 2];
    vpT[(size_t)(h * 24 + p * 3 + 0) * Nn + i] = f2bf(R[0] * x + R[1] * y + R[2] * zc + T[0]);
    vpT[(size_t)(h * 24 + p * 3 + 1) * Nn + i] = f2bf(R[3] * x + R[4] * y + R[5] * zc + T[1]);
    vpT[(size_t)(h * 24 + p * 3 + 2) * Nn + i] = f2bf(R[6] * x + R[7] * y + R[8] * zc + T[2]);
  }
}

// ===== K1c: Wb B-fragments (dense): wbf[kk][lane][e] for 16x16x32 MFMA ======
__global__ __launch_bounds__(256) void k_wbfrag(
    const float* __restrict__ Wb, ushort_t* __restrict__ wbf) {
  int t = threadIdx.x;            // 256 = 4 ksteps * 64 lanes
  int kk = t >> 6, l = t & 63;
  int h = l & 15, lk = l >> 4;
#pragma unroll
  for (int e = 0; e < 8; ++e) {
    int c = kk * 32 + lk * 8 + e;
    wbf[t * 8 + e] = (h < Hh) ? f2bf(Wb[c * Hh + h]) : (ushort_t)0;
  }
}

// ======== K2: fused flash, block per i, 8 waves; z via global/L3 =============
// Phase 1 (no barrier): wave w computes logits for j in [64w,64w+64)
// Phase 2: per-wave softmax -> P (bf16, XOR-swz LDS [16][512]) + m/l
// Phase 3: 2 barriers: merge M/L; rescale own P slice; barrier
// Phase 4 (no barrier): attend, wave owns 5 col-tiles (acc[5])
__global__ __launch_bounds__(512, 4) void k_fused3(
    const float* __restrict__ z, const ushort_t* __restrict__ eqb,
    const ushort_t* __restrict__ ekb, const ushort_t* __restrict__ wbf,
    const float* __restrict__ mk,
    const ushort_t* __restrict__ vT, const ushort_t* __restrict__ vpT,
    const float* __restrict__ rot, const float* __restrict__ trans,
    float* __restrict__ feat) {
  __shared__ float smemf[4672];                    // 18688 B
  char*  pB   = (char*)smemf;                      // P: [16][512] u16, swizzled
  float* mb   = smemf + 4096;                      // [8][16]
  float* lb   = smemf + 4224;                      // [8][16]
  float* Mv   = smemf + 4352;                      // [16]
  float* Lv   = smemf + 4368;                      // [16] = 1/L (0 for pad heads)
  float* optg = smemf + 4384;                      // [288]

  int i = blockIdx.x, tid = threadIdx.x;
  int l = tid & 63, w = tid >> 6;                  // 8 waves
  int cl = l & 15, lk = l >> 4;
  float* Fi = feat + (size_t)i * FIN;
  const float* zb = z + (size_t)i * Nn * CZ;
  int swz = (cl & 7) << 4;

  bf16x8 zer;
#pragma unroll
  for (int e = 0; e < 8; ++e) zer[e] = 0;

  bf16x8 wbreg[4];
#pragma unroll
  for (int kk = 0; kk < 4; ++kk)
    wbreg[kk] = *(const bf16x8*)&wbf[(kk * 64 + l) * 8];
  bf16x8 eqsel = zer;
  if (cl < Hh) eqsel = *(const bf16x8*)&eqb[((size_t)i * Hh + cl) * 32 + lk * 8];

  // ---- Phase 1: logits for wave's 64 j (4 groups of 16) ----
  float v[4][4];
#pragma unroll
  for (int cg = 0; cg < 4; ++cg) {
    int jt = w * 64 + cg * 16;
    int jrow = jt + cl;                            // A row (global j)
    f32x4 dl = {0.f, 0.f, 0.f, 0.f};
#pragma unroll
    for (int kk = 0; kk < 4; ++kk) {
      const float4* zp = (const float4*)(zb + (size_t)jrow * CZ + (kk * 4 + lk) * 8);
      float4 x0 = zp[0], x1 = zp[1];
      bf16x8 a;
      a[0] = (short)f2bf(x0.x); a[1] = (short)f2bf(x0.y);
      a[2] = (short)f2bf(x0.z); a[3] = (short)f2bf(x0.w);
      a[4] = (short)f2bf(x1.x); a[5] = (short)f2bf(x1.y);
      a[6] = (short)f2bf(x1.z); a[7] = (short)f2bf(x1.w);
      dl = __builtin_amdgcn_mfma_f32_16x16x32_bf16(a, wbreg[kk], dl, 0, 0, 0);
    }
#pragma unroll
    for (int hp = 0; hp < Hh; ++hp) {
      bf16x8 a = *(const bf16x8*)&ekb[((size_t)jrow * Hh + hp) * 32 + lk * 8];
      bf16x8 b = (cl == hp) ? eqsel : zer;
      dl = __builtin_amdgcn_mfma_f32_16x16x32_bf16(a, b, dl, 0, 0, 0);
    }
    int jb = jt + lk * 4;                          // D row base (j)
    if (cl < Hh) {
#pragma unroll
      for (int r = 0; r < 4; ++r) v[cg][r] = W_L * (dl[r] + mk[(jb + r) * Hh + cl]);
    } else {
#pragma unroll
      for (int r = 0; r < 4; ++r) v[cg][r] = -1e30f;
    }
  }

  // ---- Phase 2: per-wave softmax over 64 j (head = cl) ----
  float m_w = v[0][0];
#pragma unroll
  for (int cg = 0; cg < 4; ++cg)
#pragma unroll
    for (int r = 0; r < 4; ++r) m_w = fmaxf(m_w, v[cg][r]);
  m_w = fmaxf(m_w, __shfl_xor(m_w, 16));
  m_w = fmaxf(m_w, __shfl_xor(m_w, 32));

  float ps = 0.f;
#pragma unroll
  for (int cg = 0; cg < 4; ++cg) {
    int j = w * 64 + cg * 16 + lk * 4;
    ushort_t p0 = f2bf(__expf(v[cg][0] - m_w));
    ushort_t p1 = f2bf(__expf(v[cg][1] - m_w));
    ushort_t p2 = f2bf(__expf(v[cg][2] - m_w));
    ushort_t p3 = f2bf(__expf(v[cg][3] - m_w));
    ps += bf2f(p0) + bf2f(p1) + bf2f(p2) + bf2f(p3);
    uint2 d;
    d.x = (unsigned int)p0 | ((unsigned int)p1 << 16);
    d.y = (unsigned int)p2 | ((unsigned int)p3 << 16);
    *(uint2*)&pB[(cl * 1024 + j * 2) ^ swz] = d;
  }
  ps += __shfl_xor(ps, 16);
  ps += __shfl_xor(ps, 32);
  if (lk == 0) { mb[w * 16 + cl] = m_w; lb[w * 16 + cl] = ps; }
  __syncthreads();                                 // #1

  if (tid < 16) {
    float M = mb[tid];
#pragma unroll
    for (int ww = 1; ww < 8; ++ww) M = fmaxf(M, mb[ww * 16 + tid]);
    float L = 0.f;
#pragma unroll
    for (int ww = 0; ww < 8; ++ww) L += lb[ww * 16 + tid] * __expf(mb[ww * 16 + tid] - M);
    Mv[tid] = M;
    Lv[tid] = (tid < Hh) ? 1.f / L : 0.f;
  }
  __syncthreads();                                 // #2

  // ---- Phase 3: rescale own P slice by exp(m_w - M) ----
  float sf = __expf(m_w - Mv[cl]);
#pragma unroll
  for (int q = 0; q < 4; ++q) {
    int j = w * 64 + lk * 16 + q * 4;
    unsigned int off = (unsigned int)(cl * 1024 + j * 2) ^ swz;
    uint2 d = *(uint2*)&pB[off];
    ushort_t q0 = f2bf(bf2f((ushort_t)(d.x & 0xffff)) * sf);
    ushort_t q1 = f2bf(bf2f((ushort_t)(d.x >> 16)) * sf);
    ushort_t q2 = f2bf(bf2f((ushort_t)(d.y & 0xffff)) * sf);
    ushort_t q3 = f2bf(bf2f((ushort_t)(d.y >> 16)) * sf);
    d.x = (unsigned int)q0 | ((unsigned int)q1 << 16);
    d.y = (unsigned int)q2 | ((unsigned int)q3 << 16);
    *(uint2*)&pB[off] = d;
  }
  __syncthreads();                                 // #3

  // ---- Phase 4: attend, wave owns col-tiles t = w + 8n ----
  f32x4 acc[5];
#pragma unroll
  for (int n = 0; n < 5; ++n) acc[n] = (f32x4){0.f, 0.f, 0.f, 0.f};

  for (int kk = 0; kk < 16; ++kk) {
    int koff = kk * 32 + lk * 8;
    bf16x8 af = *(const bf16x8*)&pB[(cl * 1024 + koff * 2) ^ swz];
#pragma unroll
    for (int n = 0; n < 5; ++n) {
      int t = w + n * 8;
      if (t < 38) {
        bf16x8 bf;
        if (t < 8) {                               // o_pair: z^T from global/L3
          const float* zc = zb + (size_t)koff * CZ + t * 16 + cl;
#pragma unroll
          for (int e = 0; e < 8; ++e) bf[e] = (short)f2bf(zc[e * CZ]);
        } else if (t < 20) {
          bf = *(const bf16x8*)(vT + (size_t)((t - 8) * 16 + cl) * Nn + koff);
        } else {
          bf = *(const bf16x8*)(vpT + (size_t)((t - 20) * 16 + cl) * Nn + koff);
        }
        acc[n] = __builtin_amdgcn_mfma_f32_16x16x32_bf16(af, bf, acc[n], 0, 0, 0);
      }
    }
  }

  // ---- finalize: normalize by 1/L, write ----
  float rl[4];
#pragma unroll
  for (int r = 0; r < 4; ++r) rl[r] = Lv[lk * 4 + r];
#pragma unroll
  for (int n = 0; n < 5; ++n) {
    int t = w + n * 8;
    if (t < 38) {
      if (t < 8) {
        int c = t * 16 + cl;
#pragma unroll
        for (int r = 0; r < 4; ++r) {
          int h = lk * 4 + r;
          if (h < Hh) Fi[h * CZ + c] = acc[n][r] * rl[r];
        }
      } else if (t < 20) {
        int h = t - 8;
        if (lk == (h >> 2)) Fi[1536 + h * CH + cl] = acc[n][h & 3] * rl[h & 3];
      } else {
        int cp = (t - 20) * 16 + cl;
        int h = cp / 24;
        if (lk == (h >> 2)) optg[cp] = acc[n][h & 3] * rl[h & 3];
      }
    }
  }
  __syncthreads();                                 // #4

  if (tid < 96) {
    int h = tid >> 3, p = tid & 7;
    int cp = h * 24 + p * 3;
    float g0 = optg[cp + 0] - trans[i * 3 + 0];
    float g1 = optg[cp + 1] - trans[i * 3 + 1];
    float g2 = optg[cp + 2] - trans[i * 3 + 2];
    const float* R = rot + i * 9;
    float ss = 0.f;
#pragma unroll
    for (int nn2 = 0; nn2 < 3; ++nn2) {
      float o = R[nn2] * g0 + R[3 + nn2] * g1 + R[6 + nn2] * g2;   // R^T (g - t)
      Fi[1728 + cp + nn2] = o;
      ss += o * o;
    }
    Fi[2016 + h * 8 + p] = sqrtf(ss + 1e-12f);
  }
}

// ============ K5a: out partials  part[fs][i][o] = feat[f-slice] @ Wf ========
__global__ __launch_bounds__(384) void k_out_partial(
    const float* __restrict__ feat, const float* __restrict__ Wf,
    float* __restrict__ part) {
  int fs = blockIdx.x;                     // 0..7 (f-slice of 264)
  int i0 = blockIdx.y * 8;
  int o = threadIdx.x;                     // 0..383
  float acc[8];
#pragma unroll
  for (int ii = 0; ii < 8; ++ii) acc[ii] = 0.f;
  int f0 = fs * 264;
#pragma unroll 4
  for (int f = f0; f < f0 + 264; ++f) {
    float w = Wf[(size_t)f * CS + o];
#pragma unroll
    for (int ii = 0; ii < 8; ++ii) acc[ii] += w * feat[(size_t)(i0 + ii) * FIN + f];
  }
#pragma unroll
  for (int ii = 0; ii < 8; ++ii)
    part[((size_t)fs * Nn + i0 + ii) * CS + o] = acc[ii];
}

// ============ K5b: reduce partials + bias -> out ============================
__global__ __launch_bounds__(256) void k_out_reduce(
    const float* __restrict__ part, const float* __restrict__ bf,
    float* __restrict__ out) {
  int idx = blockIdx.x * 256 + threadIdx.x;        // < 512*384
  float s = bf[idx % CS];
#pragma unroll
  for (int fs = 0; fs < 8; ++fs) s += part[(size_t)fs * (Nn * CS) + idx];
  out[idx] = s;
}

// ============================ launcher ======================================
extern "C" void kernel_launch(void* const* d_in, const int* in_sizes, int n_in,
                              void* d_out, int out_size, void* d_ws, size_t ws_size,
                              hipStream_t stream) {
  const float* s_i   = (const float*)d_in[0];
  const float* z_ij  = (const float*)d_in[1];
  const float* rot   = (const float*)d_in[2];
  const float* trans = (const float*)d_in[3];
  const float* Wq    = (const float*)d_in[4];
  const float* Wk    = (const float*)d_in[5];
  const float* Wv    = (const float*)d_in[6];
  const float* Wqp   = (const float*)d_in[7];
  const float* Wkp   = (const float*)d_in[8];
  const float* Wvp   = (const float*)d_in[9];
  const float* Wb    = (const float*)d_in[10];
  const float* gamma = (const float*)d_in[11];
  const float* Wf    = (const float*)d_in[12];
  const float* bf    = (const float*)d_in[13];
  float* out = (float*)d_out;

  float* w = (float*)d_ws;
  float*    P    = w + OFF_P;
  float*    mq   = w + OFF_MQ;
  float*    mk   = w + OFF_MK;
  ushort_t* vT   = (ushort_t*)(w + OFF_VT);
  ushort_t* vpT  = (ushort_t*)(w + OFF_VPT);
  float*    feat = w + OFF_FEAT;
  float*    lg   = w + OFF_LOG;     // K5 partials
  ushort_t* ekb  = (ushort_t*)(w + OFF_EKB);
  ushort_t* eqb  = (ushort_t*)(w + OFF_EQB);
  ushort_t* wbf  = (ushort_t*)(w + OFF_WBF);

  k_proj<<<dim3(3, 64), 384, 0, stream>>>(s_i, Wq, Wk, Wv, Wqp, Wkp, Wvp, P);
  k_prep<<<96, 64, 0, stream>>>(P, rot, trans, gamma, eqb, ekb, mq, mk, vT, vpT);
  k_wbfrag<<<1, 256, 0, stream>>>(Wb, wbf);
  k_fused3<<<512, 512, 0, stream>>>(z_ij, eqb, ekb, wbf, mk, vT, vpT, rot, trans, feat);
  k_out_partial<<<dim3(8, 64), 384, 0, stream>>>(feat, Wf, lg);
  k_out_reduce<<<768, 256, 0, stream>>>(lg, bf, out);
}

// Round 9
// 124.866 us; speedup vs baseline: 1.8677x; 1.3405x over previous
//
#include <hip/hip_runtime.h>
#include <hip/hip_bf16.h>
#include <math.h>

#define Nn    512
#define CS    384
#define CZ    128
#define CH    16
#define Hh    12
#define PQ    4
#define PV    8
#define NCOL  1152   // 192*3 + 144*2 + 288
#define FIN   2112

#define W_C   0.23570226039551584f   // sqrt(2/(9*4))
#define W_L   0.5773502691896258f    // sqrt(1/3)

typedef unsigned short ushort_t;
typedef __attribute__((ext_vector_type(8))) short bf16x8;
typedef __attribute__((ext_vector_type(4))) float f32x4;

// ---------------- workspace layout (float offsets) ----------------
// P 589824 | mq 6144 | mk 6144 | vT 49152 | vpT 73728 | (feat f32 region unused)
// s16 98304 | WcT 221184 | WfT 405504 | f16 540672 | ekb/eqb 98304 | wbf 1024
#define OFF_P      0u
#define OFF_MQ     589824u
#define OFF_MK     595968u
#define OFF_VT     602112u      // v16T  [192][512] bf16
#define OFF_VPT    651264u      // vpgT  [288][512] bf16
#define OFF_S16    1830912u     // s bf16 [512][384]      = 98304 floats
#define OFF_WCT    1929216u     // WcatT bf16 [1152][384] = 221184 floats
#define OFF_WFT    2150400u     // WfT bf16 [384][2112]   = 405504 floats
#define OFF_F16    2555904u     // feat bf16 [512][2112]  = 540672 floats (ends 3096576)
#define OFF_EKB    21755904u
#define OFF_EQB    21854208u
#define OFF_WBF    21952512u

__device__ inline ushort_t f2bf(float f) {
  __hip_bfloat16 h = __float2bfloat16(f);
  return *reinterpret_cast<ushort_t*>(&h);
}
__device__ inline float bf2f(ushort_t u) {
  unsigned int x = ((unsigned int)u) << 16;
  return __uint_as_float(x);
}

// ============ K0a: s_i -> bf16 ==============================================
__global__ __launch_bounds__(256) void k_s16(
    const float* __restrict__ s, ushort_t* __restrict__ s16) {
  int idx = blockIdx.x * 256 + threadIdx.x;        // < 196608
  s16[idx] = f2bf(s[idx]);
}

// ============ K0b: WcatT[col][k] bf16 from 6 weight arrays ==================
__global__ __launch_bounds__(384) void k_wcatT(
    const float* __restrict__ Wq, const float* __restrict__ Wk,
    const float* __restrict__ Wv, const float* __restrict__ Wqp,
    const float* __restrict__ Wkp, const float* __restrict__ Wvp,
    ushort_t* __restrict__ WcatT) {
  int col = blockIdx.x;                            // 0..1151
  int k = threadIdx.x;                             // 0..383
  float v;
  if      (col < 192)  v = Wq [k * 192 + col];
  else if (col < 384)  v = Wk [k * 192 + col - 192];
  else if (col < 576)  v = Wv [k * 192 + col - 384];
  else if (col < 720)  v = Wqp[k * 144 + col - 576];
  else if (col < 864)  v = Wkp[k * 144 + col - 720];
  else                 v = Wvp[k * 288 + col - 864];
  WcatT[(size_t)col * CS + k] = f2bf(v);
}

// ============ K0c: WfT[o][f] bf16 from Wf[f][o] =============================
__global__ __launch_bounds__(256) void k_wfT(
    const float* __restrict__ Wf, ushort_t* __restrict__ WfT) {
  int o = blockIdx.x;                              // 0..383
  for (int f = threadIdx.x; f < FIN; f += 256)
    WfT[(size_t)o * FIN + f] = f2bf(Wf[(size_t)f * CS + o]);
}

// ============ K1: proj via MFMA: P = s16 @ WcatT^T (f32 out) ================
__global__ __launch_bounds__(64) void k_projm(
    const ushort_t* __restrict__ s16, const ushort_t* __restrict__ WcatT,
    float* __restrict__ P) {
  int colt = blockIdx.x;                           // 0..71
  int i0 = blockIdx.y * 16;                        // 0..496
  int l = threadIdx.x;
  int cl = l & 15, lk = l >> 4;
  f32x4 acc = {0.f, 0.f, 0.f, 0.f};
  const ushort_t* arow = s16 + (size_t)(i0 + cl) * CS;
  const ushort_t* brow = WcatT + (size_t)(colt * 16 + cl) * CS;
#pragma unroll
  for (int kk = 0; kk < 12; ++kk) {
    bf16x8 a = *(const bf16x8*)(arow + kk * 32 + lk * 8);
    bf16x8 b = *(const bf16x8*)(brow + kk * 32 + lk * 8);
    acc = __builtin_amdgcn_mfma_f32_16x16x32_bf16(a, b, acc, 0, 0, 0);
  }
#pragma unroll
  for (int r = 0; r < 4; ++r)
    P[(size_t)(i0 + lk * 4 + r) * NCOL + colt * 16 + cl] = acc[r];
}

// ===== K1b: rigid transforms -> eqb/ekb bf16, mq/mk, v16T, vpgT =============
__global__ __launch_bounds__(64) void k_prep(
    const float* __restrict__ P, const float* __restrict__ rot,
    const float* __restrict__ trans, const float* __restrict__ gamma,
    ushort_t* __restrict__ eqb, ushort_t* __restrict__ ekb,
    float* __restrict__ mq, float* __restrict__ mk,
    ushort_t* __restrict__ vT, ushort_t* __restrict__ vpT) {
  int gid = blockIdx.x * 64 + threadIdx.x;        // < 6144
  int i = gid / Hh, h = gid % Hh;
  const float* Pi = P + (size_t)i * NCOL;
  float R[9], T[3];
#pragma unroll
  for (int m = 0; m < 9; ++m) R[m] = rot[i * 9 + m];
#pragma unroll
  for (int m = 0; m < 3; ++m) T[m] = trans[i * 3 + m];
  float cg = W_C * gamma[h];

  ushort_t* eq = eqb + (size_t)gid * 32;
  ushort_t* ek = ekb + (size_t)gid * 32;
#pragma unroll
  for (int d = 0; d < CH; ++d) eq[d] = f2bf(Pi[h * CH + d] * 0.25f);   // q/sqrt(16)
#pragma unroll
  for (int d = 0; d < CH; ++d) ek[d] = f2bf(Pi[192 + h * CH + d]);     // k
  float sq = 0.f, sk = 0.f;
#pragma unroll
  for (int p = 0; p < PQ; ++p) {
    float x = Pi[576 + h * 12 + p * 3 + 0];
    float y = Pi[576 + h * 12 + p * 3 + 1];
    float zc = Pi[576 + h * 12 + p * 3 + 2];
    float gx = R[0] * x + R[1] * y + R[2] * zc + T[0];
    float gy = R[3] * x + R[4] * y + R[5] * zc + T[1];
    float gz = R[6] * x + R[7] * y + R[8] * zc + T[2];
    eq[16 + p * 3 + 0] = f2bf(cg * gx);
    eq[16 + p * 3 + 1] = f2bf(cg * gy);
    eq[16 + p * 3 + 2] = f2bf(cg * gz);
    sq += gx * gx + gy * gy + gz * gz;
  }
#pragma unroll
  for (int p = 0; p < PQ; ++p) {
    float x = Pi[720 + h * 12 + p * 3 + 0];
    float y = Pi[720 + h * 12 + p * 3 + 1];
    float zc = Pi[720 + h * 12 + p * 3 + 2];
    float gx = R[0] * x + R[1] * y + R[2] * zc + T[0];
    float gy = R[3] * x + R[4] * y + R[5] * zc + T[1];
    float gz = R[6] * x + R[7] * y + R[8] * zc + T[2];
    ek[16 + p * 3 + 0] = f2bf(gx);
    ek[16 + p * 3 + 1] = f2bf(gy);
    ek[16 + p * 3 + 2] = f2bf(gz);
    sk += gx * gx + gy * gy + gz * gz;
  }
#pragma unroll
  for (int d = 28; d < 32; ++d) { eq[d] = 0; ek[d] = 0; }
  mq[gid] = -0.5f * cg * sq;
  mk[gid] = -0.5f * cg * sk;

#pragma unroll
  for (int d = 0; d < CH; ++d)
    vT[(size_t)(h * CH + d) * Nn + i] = f2bf(Pi[384 + h * CH + d]);
#pragma unroll
  for (int p = 0; p < PV; ++p) {
    float x = Pi[864 + h * 24 + p * 3 + 0];
    float y = Pi[864 + h * 24 + p * 3 + 1];
    float zc = Pi[864 + h * 24 + p * 3 + 2];
    vpT[(size_t)(h * 24 + p * 3 + 0) * Nn + i] = f2bf(R[0] * x + R[1] * y + R[2] * zc + T[0]);
    vpT[(size_t)(h * 24 + p * 3 + 1) * Nn + i] = f2bf(R[3] * x + R[4] * y + R[5] * zc + T[1]);
    vpT[(size_t)(h * 24 + p * 3 + 2) * Nn + i] = f2bf(R[6] * x + R[7] * y + R[8] * zc + T[2]);
  }
}

// ===== K1c: Wb B-fragments (dense): wbf[kk][lane][e] for 16x16x32 MFMA ======
__global__ __launch_bounds__(256) void k_wbfrag(
    const float* __restrict__ Wb, ushort_t* __restrict__ wbf) {
  int t = threadIdx.x;            // 256 = 4 ksteps * 64 lanes
  int kk = t >> 6, l = t & 63;
  int h = l & 15, lk = l >> 4;
#pragma unroll
  for (int e = 0; e < 8; ++e) {
    int c = kk * 32 + lk * 8 + e;
    wbf[t * 8 + e] = (h < Hh) ? f2bf(Wb[c * Hh + h]) : (ushort_t)0;
  }
}

// ======== K2: fused flash, block per i, 8 waves; z via global/L3 =============
__global__ __launch_bounds__(512, 4) void k_fused3(
    const float* __restrict__ z, const ushort_t* __restrict__ eqb,
    const ushort_t* __restrict__ ekb, const ushort_t* __restrict__ wbf,
    const float* __restrict__ mk,
    const ushort_t* __restrict__ vT, const ushort_t* __restrict__ vpT,
    const float* __restrict__ rot, const float* __restrict__ trans,
    ushort_t* __restrict__ feat16) {
  __shared__ float smemf[4672];                    // 18688 B
  char*  pB   = (char*)smemf;                      // P: [16][512] u16, swizzled
  float* mb   = smemf + 4096;                      // [8][16]
  float* lb   = smemf + 4224;                      // [8][16]
  float* Mv   = smemf + 4352;                      // [16]
  float* Lv   = smemf + 4368;                      // [16] = 1/L (0 for pad heads)
  float* optg = smemf + 4384;                      // [288]

  int i = blockIdx.x, tid = threadIdx.x;
  int l = tid & 63, w = tid >> 6;                  // 8 waves
  int cl = l & 15, lk = l >> 4;
  ushort_t* Fi = feat16 + (size_t)i * FIN;
  const float* zb = z + (size_t)i * Nn * CZ;
  int swz = (cl & 7) << 4;

  bf16x8 zer;
#pragma unroll
  for (int e = 0; e < 8; ++e) zer[e] = 0;

  bf16x8 wbreg[4];
#pragma unroll
  for (int kk = 0; kk < 4; ++kk)
    wbreg[kk] = *(const bf16x8*)&wbf[(kk * 64 + l) * 8];
  bf16x8 eqsel = zer;
  if (cl < Hh) eqsel = *(const bf16x8*)&eqb[((size_t)i * Hh + cl) * 32 + lk * 8];

  // ---- Phase 1: logits for wave's 64 j (4 groups of 16) ----
  float v[4][4];
#pragma unroll
  for (int cg = 0; cg < 4; ++cg) {
    int jt = w * 64 + cg * 16;
    int jrow = jt + cl;                            // A row (global j)
    f32x4 dl = {0.f, 0.f, 0.f, 0.f};
#pragma unroll
    for (int kk = 0; kk < 4; ++kk) {
      const float4* zp = (const float4*)(zb + (size_t)jrow * CZ + (kk * 4 + lk) * 8);
      float4 x0 = zp[0], x1 = zp[1];
      bf16x8 a;
      a[0] = (short)f2bf(x0.x); a[1] = (short)f2bf(x0.y);
      a[2] = (short)f2bf(x0.z); a[3] = (short)f2bf(x0.w);
      a[4] = (short)f2bf(x1.x); a[5] = (short)f2bf(x1.y);
      a[6] = (short)f2bf(x1.z); a[7] = (short)f2bf(x1.w);
      dl = __builtin_amdgcn_mfma_f32_16x16x32_bf16(a, wbreg[kk], dl, 0, 0, 0);
    }
#pragma unroll
    for (int hp = 0; hp < Hh; ++hp) {
      bf16x8 a = *(const bf16x8*)&ekb[((size_t)jrow * Hh + hp) * 32 + lk * 8];
      bf16x8 b = (cl == hp) ? eqsel : zer;
      dl = __builtin_amdgcn_mfma_f32_16x16x32_bf16(a, b, dl, 0, 0, 0);
    }
    int jb = jt + lk * 4;                          // D row base (j)
    if (cl < Hh) {
#pragma unroll
      for (int r = 0; r < 4; ++r) v[cg][r] = W_L * (dl[r] + mk[(jb + r) * Hh + cl]);
    } else {
#pragma unroll
      for (int r = 0; r < 4; ++r) v[cg][r] = -1e30f;
    }
  }

  // ---- Phase 2: per-wave softmax over 64 j (head = cl) ----
  float m_w = v[0][0];
#pragma unroll
  for (int cg = 0; cg < 4; ++cg)
#pragma unroll
    for (int r = 0; r < 4; ++r) m_w = fmaxf(m_w, v[cg][r]);
  m_w = fmaxf(m_w, __shfl_xor(m_w, 16));
  m_w = fmaxf(m_w, __shfl_xor(m_w, 32));

  float ps = 0.f;
#pragma unroll
  for (int cg = 0; cg < 4; ++cg) {
    int j = w * 64 + cg * 16 + lk * 4;
    ushort_t p0 = f2bf(__expf(v[cg][0] - m_w));
    ushort_t p1 = f2bf(__expf(v[cg][1] - m_w));
    ushort_t p2 = f2bf(__expf(v[cg][2] - m_w));
    ushort_t p3 = f2bf(__expf(v[cg][3] - m_w));
    ps += bf2f(p0) + bf2f(p1) + bf2f(p2) + bf2f(p3);
    uint2 d;
    d.x = (unsigned int)p0 | ((unsigned int)p1 << 16);
    d.y = (unsigned int)p2 | ((unsigned int)p3 << 16);
    *(uint2*)&pB[(cl * 1024 + j * 2) ^ swz] = d;
  }
  ps += __shfl_xor(ps, 16);
  ps += __shfl_xor(ps, 32);
  if (lk == 0) { mb[w * 16 + cl] = m_w; lb[w * 16 + cl] = ps; }
  __syncthreads();                                 // #1

  if (tid < 16) {
    float M = mb[tid];
#pragma unroll
    for (int ww = 1; ww < 8; ++ww) M = fmaxf(M, mb[ww * 16 + tid]);
    float L = 0.f;
#pragma unroll
    for (int ww = 0; ww < 8; ++ww) L += lb[ww * 16 + tid] * __expf(mb[ww * 16 + tid] - M);
    Mv[tid] = M;
    Lv[tid] = (tid < Hh) ? 1.f / L : 0.f;
  }
  __syncthreads();                                 // #2

  // ---- Phase 3: rescale own P slice by exp(m_w - M) ----
  float sf = __expf(m_w - Mv[cl]);
#pragma unroll
  for (int q = 0; q < 4; ++q) {
    int j = w * 64 + lk * 16 + q * 4;
    unsigned int off = (unsigned int)(cl * 1024 + j * 2) ^ swz;
    uint2 d = *(uint2*)&pB[off];
    ushort_t q0 = f2bf(bf2f((ushort_t)(d.x & 0xffff)) * sf);
    ushort_t q1 = f2bf(bf2f((ushort_t)(d.x >> 16)) * sf);
    ushort_t q2 = f2bf(bf2f((ushort_t)(d.y & 0xffff)) * sf);
    ushort_t q3 = f2bf(bf2f((ushort_t)(d.y >> 16)) * sf);
    d.x = (unsigned int)q0 | ((unsigned int)q1 << 16);
    d.y = (unsigned int)q2 | ((unsigned int)q3 << 16);
    *(uint2*)&pB[off] = d;
  }
  __syncthreads();                                 // #3

  // ---- Phase 4: attend, wave owns col-tiles t = w + 8n ----
  f32x4 acc[5];
#pragma unroll
  for (int n = 0; n < 5; ++n) acc[n] = (f32x4){0.f, 0.f, 0.f, 0.f};

  for (int kk = 0; kk < 16; ++kk) {
    int koff = kk * 32 + lk * 8;
    bf16x8 af = *(const bf16x8*)&pB[(cl * 1024 + koff * 2) ^ swz];
#pragma unroll
    for (int n = 0; n < 5; ++n) {
      int t = w + n * 8;
      if (t < 38) {
        bf16x8 bf;
        if (t < 8) {                               // o_pair: z^T from global/L3
          const float* zc = zb + (size_t)koff * CZ + t * 16 + cl;
#pragma unroll
          for (int e = 0; e < 8; ++e) bf[e] = (short)f2bf(zc[e * CZ]);
        } else if (t < 20) {
          bf = *(const bf16x8*)(vT + (size_t)((t - 8) * 16 + cl) * Nn + koff);
        } else {
          bf = *(const bf16x8*)(vpT + (size_t)((t - 20) * 16 + cl) * Nn + koff);
        }
        acc[n] = __builtin_amdgcn_mfma_f32_16x16x32_bf16(af, bf, acc[n], 0, 0, 0);
      }
    }
  }

  // ---- finalize: normalize by 1/L, write (bf16 feat) ----
  float rl[4];
#pragma unroll
  for (int r = 0; r < 4; ++r) rl[r] = Lv[lk * 4 + r];
#pragma unroll
  for (int n = 0; n < 5; ++n) {
    int t = w + n * 8;
    if (t < 38) {
      if (t < 8) {
        int c = t * 16 + cl;
#pragma unroll
        for (int r = 0; r < 4; ++r) {
          int h = lk * 4 + r;
          if (h < Hh) Fi[h * CZ + c] = f2bf(acc[n][r] * rl[r]);
        }
      } else if (t < 20) {
        int h = t - 8;
        if (lk == (h >> 2)) Fi[1536 + h * CH + cl] = f2bf(acc[n][h & 3] * rl[h & 3]);
      } else {
        int cp = (t - 20) * 16 + cl;
        int h = cp / 24;
        if (lk == (h >> 2)) optg[cp] = acc[n][h & 3] * rl[h & 3];
      }
    }
  }
  __syncthreads();                                 // #4

  if (tid < 96) {
    int h = tid >> 3, p = tid & 7;
    int cp = h * 24 + p * 3;
    float g0 = optg[cp + 0] - trans[i * 3 + 0];
    float g1 = optg[cp + 1] - trans[i * 3 + 1];
    float g2 = optg[cp + 2] - trans[i * 3 + 2];
    const float* R = rot + i * 9;
    float ss = 0.f;
#pragma unroll
    for (int nn2 = 0; nn2 < 3; ++nn2) {
      float o = R[nn2] * g0 + R[3 + nn2] * g1 + R[6 + nn2] * g2;   // R^T (g - t)
      Fi[1728 + cp + nn2] = f2bf(o);
      ss += o * o;
    }
    Fi[2016 + h * 8 + p] = f2bf(sqrtf(ss + 1e-12f));
  }
}

// ============ K5: out = feat16 @ WfT^T + bf (MFMA) ==========================
__global__ __launch_bounds__(64) void k_outm(
    const ushort_t* __restrict__ feat16, const ushort_t* __restrict__ WfT,
    const float* __restrict__ bfv, float* __restrict__ out) {
  int ot = blockIdx.x;                             // 0..23
  int i0 = blockIdx.y * 16;
  int l = threadIdx.x;
  int cl = l & 15, lk = l >> 4;
  f32x4 acc = {0.f, 0.f, 0.f, 0.f};
  const ushort_t* arow = feat16 + (size_t)(i0 + cl) * FIN;
  const ushort_t* brow = WfT + (size_t)(ot * 16 + cl) * FIN;
#pragma unroll 6
  for (int kk = 0; kk < 66; ++kk) {
    bf16x8 a = *(const bf16x8*)(arow + kk * 32 + lk * 8);
    bf16x8 b = *(const bf16x8*)(brow + kk * 32 + lk * 8);
    acc = __builtin_amdgcn_mfma_f32_16x16x32_bf16(a, b, acc, 0, 0, 0);
  }
  float bias = bfv[ot * 16 + cl];
#pragma unroll
  for (int r = 0; r < 4; ++r)
    out[(size_t)(i0 + lk * 4 + r) * CS + ot * 16 + cl] = acc[r] + bias;
}

// ============================ launcher ======================================
extern "C" void kernel_launch(void* const* d_in, const int* in_sizes, int n_in,
                              void* d_out, int out_size, void* d_ws, size_t ws_size,
                              hipStream_t stream) {
  const float* s_i   = (const float*)d_in[0];
  const float* z_ij  = (const float*)d_in[1];
  const float* rot   = (const float*)d_in[2];
  const float* trans = (const float*)d_in[3];
  const float* Wq    = (const float*)d_in[4];
  const float* Wk    = (const float*)d_in[5];
  const float* Wv    = (const float*)d_in[6];
  const float* Wqp   = (const float*)d_in[7];
  const float* Wkp   = (const float*)d_in[8];
  const float* Wvp   = (const float*)d_in[9];
  const float* Wb    = (const float*)d_in[10];
  const float* gamma = (const float*)d_in[11];
  const float* Wf    = (const float*)d_in[12];
  const float* bf    = (const float*)d_in[13];
  float* out = (float*)d_out;

  float* w = (float*)d_ws;
  float*    P    = w + OFF_P;
  float*    mq   = w + OFF_MQ;
  float*    mk   = w + OFF_MK;
  ushort_t* vT   = (ushort_t*)(w + OFF_VT);
  ushort_t* vpT  = (ushort_t*)(w + OFF_VPT);
  ushort_t* s16  = (ushort_t*)(w + OFF_S16);
  ushort_t* WcT  = (ushort_t*)(w + OFF_WCT);
  ushort_t* WfT  = (ushort_t*)(w + OFF_WFT);
  ushort_t* f16  = (ushort_t*)(w + OFF_F16);
  ushort_t* ekb  = (ushort_t*)(w + OFF_EKB);
  ushort_t* eqb  = (ushort_t*)(w + OFF_EQB);
  ushort_t* wbf  = (ushort_t*)(w + OFF_WBF);

  k_s16<<<768, 256, 0, stream>>>(s_i, s16);
  k_wcatT<<<1152, 384, 0, stream>>>(Wq, Wk, Wv, Wqp, Wkp, Wvp, WcT);
  k_wfT<<<384, 256, 0, stream>>>(Wf, WfT);
  k_projm<<<dim3(72, 32), 64, 0, stream>>>(s16, WcT, P);
  k_prep<<<96, 64, 0, stream>>>(P, rot, trans, gamma, eqb, ekb, mq, mk, vT, vpT);
  k_wbfrag<<<1, 256, 0, stream>>>(Wb, wbf);
  k_fused3<<<512, 512, 0, stream>>>(z_ij, eqb, ekb, wbf, mk, vT, vpT, rot, trans, f16);
  k_outm<<<dim3(24, 32), 64, 0, stream>>>(f16, WfT, bf, out);
}